// Round 1
// baseline (1570.104 us; speedup 1.0000x reference)
//
#include <hip/hip_runtime.h>
#include <hip/hip_bf16.h>

#define D   128
#define DM  256
#define DI  512
#define HH  512
#define KNN 10
#define NN  64
#define BQ  4096
#define BS  128
#define G4  2048   // 4*HH

__device__ __forceinline__ float sigmoidf_(float x) {
    return 1.f / (1.f + __expf(-x));
}
__device__ __forceinline__ float tanh_fast(float x) {
    x = fminf(fmaxf(x, -20.f), 20.f);
    float e = __expf(2.f * x);
    return (e - 1.f) / (e + 1.f);
}

// ---------------- neighbor encoder ----------------
// grid = B*2 blocks (row = bid>>1, side = bid&1), 256 threads
__global__ __launch_bounds__(256) void ne_kernel(
    const int* __restrict__ conn_l, const int* __restrict__ conn_r,
    const int* __restrict__ ids, const float* __restrict__ emb,
    const float* __restrict__ gcn_W, const float* __restrict__ gcn_wb,
    const float* __restrict__ gcn_b, float* __restrict__ out)
{
    int row = blockIdx.x >> 1;
    int side = blockIdx.x & 1;
    const int* conn = (side ? conn_r : conn_l) + (size_t)row * NN * 2;
    int cid = ids[row * 2 + side];

    __shared__ float cen[D];
    __shared__ float sim[NN];
    __shared__ int   selr[KNN], sele[KNN];
    __shared__ float catm[2 * D];
    __shared__ float pp[256];

    int tid = threadIdx.x;
    int wave = tid >> 6, lane = tid & 63;

    if (tid < D) cen[tid] = emb[(size_t)cid * D + tid];
    __syncthreads();

    float c0 = cen[lane * 2], c1 = cen[lane * 2 + 1];
    float csq = c0 * c0 + c1 * c1;
    #pragma unroll
    for (int off = 32; off; off >>= 1) csq += __shfl_xor(csq, off);
    float cnorm = fmaxf(sqrtf(csq), 1e-8f);

    for (int j = wave; j < NN; j += 4) {
        int eid = conn[j * 2 + 1];
        const float* e = emb + (size_t)eid * D;
        float e0 = e[lane * 2], e1 = e[lane * 2 + 1];
        float dot = c0 * e0 + c1 * e1;
        float sq = e0 * e0 + e1 * e1;
        #pragma unroll
        for (int off = 32; off; off >>= 1) {
            dot += __shfl_xor(dot, off);
            sq  += __shfl_xor(sq, off);
        }
        if (lane == 0) sim[j] = dot / (cnorm * fmaxf(sqrtf(sq), 1e-8f));
    }
    __syncthreads();

    // top-10 by (max value, min index) — matches jax.lax.top_k tie-breaking
    if (wave == 0) {
        float s = sim[lane];
        int id = lane;
        for (int k = 0; k < KNN; k++) {
            float bs = s; int bi = id;
            #pragma unroll
            for (int off = 32; off; off >>= 1) {
                float os = __shfl_xor(bs, off);
                int   oi = __shfl_xor(bi, off);
                if (os > bs || (os == bs && oi < bi)) { bs = os; bi = oi; }
            }
            if (lane == 0) { selr[k] = conn[bi * 2]; sele[k] = conn[bi * 2 + 1]; }
            if (id == bi) s = -__builtin_inff();
        }
    }
    __syncthreads();

    // mean over K of [rel ; ent]  (mean commutes with the linear einsum)
    float acc = 0.f;
    if (tid < D) {
        for (int k = 0; k < KNN; k++) acc += emb[(size_t)selr[k] * D + tid];
    } else {
        int d = tid - D;
        for (int k = 0; k < KNN; k++) acc += emb[(size_t)sele[k] * D + d];
    }
    catm[tid] = acc * (1.f / KNN);
    __syncthreads();

    // h[d] = sum_f catm[f] * W[d,f] ; split f-range over thread pairs
    int d = tid & (D - 1);
    int half = tid >> 7;
    const float4* W4  = (const float4*)(gcn_W + (size_t)d * (2 * D) + half * D);
    const float4* cm4 = (const float4*)(catm + half * D);
    float p = 0.f;
    #pragma unroll
    for (int f4 = 0; f4 < D / 4; ++f4) {
        float4 w = W4[f4]; float4 cv = cm4[f4];
        p += w.x * cv.x + w.y * cv.y + w.z * cv.z + w.w * cv.w;
    }
    pp[tid] = p;
    __syncthreads();
    if (tid < D) {
        float h = pp[tid] + pp[tid + D] + gcn_wb[tid] + gcn_b[tid];
        out[(size_t)row * (2 * D) + side * D + tid] = tanh_fast(h);
    }
}

// ---------------- support encoder (residual FFN + LayerNorm) ----------------
#define SE_ROWS 8
__global__ __launch_bounds__(256) void se_kernel(
    const float* __restrict__ x, const float* __restrict__ w1,
    const float* __restrict__ b1, const float* __restrict__ w2,
    const float* __restrict__ b2, const float* __restrict__ g,
    const float* __restrict__ b, float* __restrict__ out)
{
    __shared__ float xs[SE_ROWS][DM];
    __shared__ float t1s[SE_ROWS][DI];
    __shared__ float ys[SE_ROWS][DM];
    int tid = threadIdx.x;
    int r0 = blockIdx.x * SE_ROWS;
    for (int r = 0; r < SE_ROWS; r++) xs[r][tid] = x[(size_t)(r0 + r) * DM + tid];
    __syncthreads();

    for (int jj = 0; jj < 2; ++jj) {
        int j = tid + jj * 256;
        float acc[SE_ROWS];
        #pragma unroll
        for (int r = 0; r < SE_ROWS; r++) acc[r] = 0.f;
        const float4* w4 = (const float4*)(w1 + (size_t)j * DM);
        for (int f4 = 0; f4 < DM / 4; ++f4) {
            float4 w = w4[f4];
            #pragma unroll
            for (int r = 0; r < SE_ROWS; r++) {
                const float* xr = &xs[r][f4 * 4];
                acc[r] += w.x * xr[0] + w.y * xr[1] + w.z * xr[2] + w.w * xr[3];
            }
        }
        float bj = b1[j];
        #pragma unroll
        for (int r = 0; r < SE_ROWS; r++) t1s[r][j] = fmaxf(acc[r] + bj, 0.f);
    }
    __syncthreads();

    {
        float acc[SE_ROWS];
        #pragma unroll
        for (int r = 0; r < SE_ROWS; r++) acc[r] = 0.f;
        const float4* w4 = (const float4*)(w2 + (size_t)tid * DI);
        for (int f4 = 0; f4 < DI / 4; ++f4) {
            float4 w = w4[f4];
            #pragma unroll
            for (int r = 0; r < SE_ROWS; r++) {
                const float* tr = &t1s[r][f4 * 4];
                acc[r] += w.x * tr[0] + w.y * tr[1] + w.z * tr[2] + w.w * tr[3];
            }
        }
        float bt = b2[tid];
        #pragma unroll
        for (int r = 0; r < SE_ROWS; r++) ys[r][tid] = acc[r] + bt + xs[r][tid];
    }
    __syncthreads();

    int wave = tid >> 6, lane = tid & 63;
    for (int rr = 0; rr < 2; ++rr) {
        int r = wave * 2 + rr;
        float s = 0.f;
        #pragma unroll
        for (int e = 0; e < 4; e++) s += ys[r][e * 64 + lane];
        #pragma unroll
        for (int off = 32; off; off >>= 1) s += __shfl_xor(s, off);
        float mu = s * (1.f / DM);
        float v = 0.f;
        #pragma unroll
        for (int e = 0; e < 4; e++) {
            float dd = ys[r][e * 64 + lane] - mu;
            v += dd * dd;
        }
        #pragma unroll
        for (int off = 32; off; off >>= 1) v += __shfl_xor(v, off);
        float rstd = rsqrtf(v * (1.f / DM) + 1e-5f);
        #pragma unroll
        for (int e = 0; e < 4; e++) {
            int dd = e * 64 + lane;
            out[(size_t)(r0 + r) * DM + dd] = (ys[r][dd] - mu) * rstd * g[dd] + b[dd];
        }
    }
}

// ---------------- support_g = mean over BS rows ----------------
__global__ void sg_reduce_kernel(const float* __restrict__ se_s, float* __restrict__ sg)
{
    int tid = threadIdx.x;
    float a = 0.f;
    for (int r = 0; r < BS; r++) a += se_s[(size_t)r * DM + tid];
    sg[tid] = a * (1.f / BS);
}

// ---------------- sgW[g] = sum_j sg[j] * W_hh[g, 256+j] ----------------
__global__ __launch_bounds__(256) void sgw_kernel(
    const float* __restrict__ W_hh, const float* __restrict__ sg,
    float* __restrict__ sgW)
{
    __shared__ float s[DM];
    int tid = threadIdx.x;
    s[tid] = sg[tid];
    __syncthreads();
    int g = blockIdx.x * 256 + tid;
    const float4* w4 = (const float4*)(W_hh + (size_t)g * HH + DM);
    float acc = 0.f;
    for (int f4 = 0; f4 < DM / 4; ++f4) {
        float4 w = w4[f4];
        acc += w.x * s[f4 * 4] + w.y * s[f4 * 4 + 1] + w.z * s[f4 * 4 + 2] + w.w * s[f4 * 4 + 3];
    }
    sgW[g] = acc;
}

// ---------------- LSTM step 1 (h_r = 0): gates = q@W_ih.T + b_ih + b_hh ----------------
#define LR 8
__global__ __launch_bounds__(256) void lstm_step1_kernel(
    const float* __restrict__ qg, const float* __restrict__ W_ih,
    const float* __restrict__ b_ih, const float* __restrict__ b_hh,
    float* __restrict__ qWih_b, float* __restrict__ h_ws, float* __restrict__ c_ws)
{
    __shared__ float qs[LR][DM];
    int tid = threadIdx.x;
    int r0 = blockIdx.x * LR;
    for (int r = 0; r < LR; r++) qs[r][tid] = qg[(size_t)(r0 + r) * DM + tid];
    __syncthreads();

    for (int uu = 0; uu < 2; ++uu) {
        int u = tid + uu * 256;
        int gi = u, gf = 512 + u, gg = 1024 + u, go = 1536 + u;
        float ai[LR], af[LR], ag[LR], ao[LR];
        #pragma unroll
        for (int r = 0; r < LR; r++) { ai[r] = 0.f; af[r] = 0.f; ag[r] = 0.f; ao[r] = 0.f; }
        const float4* wi4 = (const float4*)(W_ih + (size_t)gi * DM);
        const float4* wf4 = (const float4*)(W_ih + (size_t)gf * DM);
        const float4* wg4 = (const float4*)(W_ih + (size_t)gg * DM);
        const float4* wo4 = (const float4*)(W_ih + (size_t)go * DM);
        for (int f4 = 0; f4 < DM / 4; ++f4) {
            float4 wi = wi4[f4], wf = wf4[f4], wg = wg4[f4], wo = wo4[f4];
            #pragma unroll
            for (int r = 0; r < LR; r++) {
                const float* q = &qs[r][f4 * 4];
                float q0 = q[0], q1 = q[1], q2 = q[2], q3 = q[3];
                ai[r] += wi.x * q0 + wi.y * q1 + wi.z * q2 + wi.w * q3;
                af[r] += wf.x * q0 + wf.y * q1 + wf.z * q2 + wf.w * q3;
                ag[r] += wg.x * q0 + wg.y * q1 + wg.z * q2 + wg.w * q3;
                ao[r] += wo.x * q0 + wo.y * q1 + wo.z * q2 + wo.w * q3;
            }
        }
        float bi_ = b_ih[gi] + b_hh[gi];
        float bf_ = b_ih[gf] + b_hh[gf];
        float bg_ = b_ih[gg] + b_hh[gg];
        float bo_ = b_ih[go] + b_hh[go];
        for (int r = 0; r < LR; r++) {
            float iv = ai[r] + bi_, fv = af[r] + bf_, gv = ag[r] + bg_, ov = ao[r] + bo_;
            size_t base = (size_t)(r0 + r) * G4;
            qWih_b[base + gi] = iv;
            qWih_b[base + gf] = fv;
            qWih_b[base + gg] = gv;
            qWih_b[base + go] = ov;
            float cv = sigmoidf_(iv) * tanh_fast(gv);  // c_prev = 0
            c_ws[(size_t)(r0 + r) * HH + u] = cv;
            if (uu == 0) {
                float hn = sigmoidf_(ov) * tanh_fast(cv);
                h_ws[(size_t)(r0 + r) * DM + u] = qs[r][u] + hn;
            }
        }
    }
}

// ---------------- LSTM steps 2..4: gates = qWih_b + sgW + h @ W_hh[:, :256].T ----------------
__global__ __launch_bounds__(256) void lstm_step_kernel(
    const float* __restrict__ qg, const float* __restrict__ W_hh,
    const float* __restrict__ qWih_b, const float* __restrict__ sgW,
    float* __restrict__ h_ws, float* __restrict__ c_ws)
{
    __shared__ float hs[LR][DM];
    int tid = threadIdx.x;
    int r0 = blockIdx.x * LR;
    for (int r = 0; r < LR; r++) hs[r][tid] = h_ws[(size_t)(r0 + r) * DM + tid];
    __syncthreads();

    for (int uu = 0; uu < 2; ++uu) {
        int u = tid + uu * 256;
        int gi = u, gf = 512 + u, gg = 1024 + u, go = 1536 + u;
        float ai[LR], af[LR], ag[LR], ao[LR];
        #pragma unroll
        for (int r = 0; r < LR; r++) { ai[r] = 0.f; af[r] = 0.f; ag[r] = 0.f; ao[r] = 0.f; }
        const float4* wi4 = (const float4*)(W_hh + (size_t)gi * HH);
        const float4* wf4 = (const float4*)(W_hh + (size_t)gf * HH);
        const float4* wg4 = (const float4*)(W_hh + (size_t)gg * HH);
        const float4* wo4 = (const float4*)(W_hh + (size_t)go * HH);
        for (int f4 = 0; f4 < DM / 4; ++f4) {
            float4 wi = wi4[f4], wf = wf4[f4], wg = wg4[f4], wo = wo4[f4];
            #pragma unroll
            for (int r = 0; r < LR; r++) {
                const float* q = &hs[r][f4 * 4];
                float q0 = q[0], q1 = q[1], q2 = q[2], q3 = q[3];
                ai[r] += wi.x * q0 + wi.y * q1 + wi.z * q2 + wi.w * q3;
                af[r] += wf.x * q0 + wf.y * q1 + wf.z * q2 + wf.w * q3;
                ag[r] += wg.x * q0 + wg.y * q1 + wg.z * q2 + wg.w * q3;
                ao[r] += wo.x * q0 + wo.y * q1 + wo.z * q2 + wo.w * q3;
            }
        }
        float sgi = sgW[gi], sgf = sgW[gf], sgg = sgW[gg], sgo = sgW[go];
        for (int r = 0; r < LR; r++) {
            size_t base = (size_t)(r0 + r) * G4;
            float iv = ai[r] + qWih_b[base + gi] + sgi;
            float fv = af[r] + qWih_b[base + gf] + sgf;
            float gv = ag[r] + qWih_b[base + gg] + sgg;
            float ov = ao[r] + qWih_b[base + go] + sgo;
            size_t cix = (size_t)(r0 + r) * HH + u;
            float cv = sigmoidf_(fv) * c_ws[cix] + sigmoidf_(iv) * tanh_fast(gv);
            c_ws[cix] = cv;
            if (uu == 0) {
                float hn = sigmoidf_(ov) * tanh_fast(cv);
                h_ws[(size_t)(r0 + r) * DM + u] = qg[(size_t)(r0 + r) * DM + u] + hn;
            }
        }
    }
}

// ---------------- final cosine ----------------
__global__ __launch_bounds__(256) void final_kernel(
    const float* __restrict__ h_ws, const float* __restrict__ sg,
    float* __restrict__ outp)
{
    __shared__ float sgs[DM];
    int tid = threadIdx.x;
    sgs[tid] = sg[tid];
    __syncthreads();
    int wave = tid >> 6, lane = tid & 63;
    float sn = 0.f;
    #pragma unroll
    for (int e = 0; e < 4; e++) { float v = sgs[e * 64 + lane]; sn += v * v; }
    #pragma unroll
    for (int off = 32; off; off >>= 1) sn += __shfl_xor(sn, off);
    float sgnorm = fmaxf(sqrtf(sn), 1e-12f);

    int row = blockIdx.x * 4 + wave;
    const float* h = h_ws + (size_t)row * DM;
    float dot = 0.f, hn = 0.f;
    #pragma unroll
    for (int e = 0; e < 4; e++) {
        float hv = h[e * 64 + lane];
        dot += hv * sgs[e * 64 + lane];
        hn += hv * hv;
    }
    #pragma unroll
    for (int off = 32; off; off >>= 1) { dot += __shfl_xor(dot, off); hn += __shfl_xor(hn, off); }
    if (lane == 0) outp[row] = dot / (fmaxf(sqrtf(hn), 1e-12f) * sgnorm);
}

extern "C" void kernel_launch(void* const* d_in, const int* in_sizes, int n_in,
                              void* d_out, int out_size, void* d_ws, size_t ws_size,
                              hipStream_t stream)
{
    const int* query    = (const int*)d_in[0];
    const int* support  = (const int*)d_in[1];
    const int* q_l_conn = (const int*)d_in[2];
    const int* q_r_conn = (const int*)d_in[4];
    const int* s_l_conn = (const int*)d_in[6];
    const int* s_r_conn = (const int*)d_in[8];
    const float* emb    = (const float*)d_in[10];
    const float* gcn_W  = (const float*)d_in[11];
    const float* gcn_wb = (const float*)d_in[12];
    const float* gcn_b  = (const float*)d_in[13];
    const float* se_w1  = (const float*)d_in[14];
    const float* se_b1  = (const float*)d_in[15];
    const float* se_w2  = (const float*)d_in[16];
    const float* se_b2  = (const float*)d_in[17];
    const float* ln_g   = (const float*)d_in[18];
    const float* ln_b   = (const float*)d_in[19];
    const float* W_ih   = (const float*)d_in[20];
    const float* W_hh   = (const float*)d_in[21];
    const float* b_ih   = (const float*)d_in[22];
    const float* b_hh   = (const float*)d_in[23];
    float* out = (float*)d_out;

    float* ws = (float*)d_ws;
    float* q_nb   = ws; ws += (size_t)BQ * DM;
    float* s_nb   = ws; ws += (size_t)BS * DM;
    float* se_s   = ws; ws += (size_t)BS * DM;
    float* sg     = ws; ws += DM;
    float* qg     = ws; ws += (size_t)BQ * DM;
    float* sgW    = ws; ws += G4;
    float* qWih_b = ws; ws += (size_t)BQ * G4;
    float* h_ws   = ws; ws += (size_t)BQ * DM;
    float* c_ws   = ws; ws += (size_t)BQ * HH;

    ne_kernel<<<BQ * 2, 256, 0, stream>>>(q_l_conn, q_r_conn, query, emb,
                                          gcn_W, gcn_wb, gcn_b, q_nb);
    ne_kernel<<<BS * 2, 256, 0, stream>>>(s_l_conn, s_r_conn, support, emb,
                                          gcn_W, gcn_wb, gcn_b, s_nb);
    se_kernel<<<BS / SE_ROWS, 256, 0, stream>>>(s_nb, se_w1, se_b1, se_w2, se_b2,
                                                ln_g, ln_b, se_s);
    sg_reduce_kernel<<<1, 256, 0, stream>>>(se_s, sg);
    se_kernel<<<BQ / SE_ROWS, 256, 0, stream>>>(q_nb, se_w1, se_b1, se_w2, se_b2,
                                                ln_g, ln_b, qg);
    sgw_kernel<<<G4 / 256, 256, 0, stream>>>(W_hh, sg, sgW);
    lstm_step1_kernel<<<BQ / LR, 256, 0, stream>>>(qg, W_ih, b_ih, b_hh,
                                                   qWih_b, h_ws, c_ws);
    for (int s = 0; s < 3; s++)
        lstm_step_kernel<<<BQ / LR, 256, 0, stream>>>(qg, W_hh, qWih_b, sgW,
                                                      h_ws, c_ws);
    final_kernel<<<BQ / 4, 256, 0, stream>>>(h_ws, sg, out);
}

// Round 2
// 708.179 us; speedup vs baseline: 2.2171x; 2.2171x over previous
//
#include <hip/hip_runtime.h>
#include <hip/hip_bf16.h>

#define D   128
#define DM  256
#define DI  512
#define HH  512
#define KNN 10
#define NN  64
#define BQ  4096
#define BS  128
#define G4  2048   // 4*HH
#define GN  2048   // GEMM N
#define GK  256    // GEMM K

__device__ __forceinline__ float sigmoidf_(float x) {
    return 1.f / (1.f + __expf(-x));
}
__device__ __forceinline__ float tanh_fast(float x) {
    x = fminf(fmaxf(x, -20.f), 20.f);
    float e = __expf(2.f * x);
    return (e - 1.f) / (e + 1.f);
}
__device__ __forceinline__ ushort f2bf(float x) {
    union { float f; unsigned u; } v; v.f = x;
    unsigned r = (v.u + 0x7fffu + ((v.u >> 16) & 1u)) >> 16;  // RNE
    return (ushort)r;
}

typedef __bf16  bf16x8  __attribute__((ext_vector_type(8)));
typedef float   floatx4 __attribute__((ext_vector_type(4)));

// ---------------- neighbor encoder ----------------
__global__ __launch_bounds__(256) void ne_kernel(
    const int* __restrict__ conn_l, const int* __restrict__ conn_r,
    const int* __restrict__ ids, const float* __restrict__ emb,
    const float* __restrict__ gcn_W, const float* __restrict__ gcn_wb,
    const float* __restrict__ gcn_b, float* __restrict__ out)
{
    int row = blockIdx.x >> 1;
    int side = blockIdx.x & 1;
    const int* conn = (side ? conn_r : conn_l) + (size_t)row * NN * 2;
    int cid = ids[row * 2 + side];

    __shared__ float cen[D];
    __shared__ float sim[NN];
    __shared__ int   selr[KNN], sele[KNN];
    __shared__ float catm[2 * D];
    __shared__ float pp[256];

    int tid = threadIdx.x;
    int wave = tid >> 6, lane = tid & 63;

    if (tid < D) cen[tid] = emb[(size_t)cid * D + tid];
    __syncthreads();

    float c0 = cen[lane * 2], c1 = cen[lane * 2 + 1];
    float csq = c0 * c0 + c1 * c1;
    #pragma unroll
    for (int off = 32; off; off >>= 1) csq += __shfl_xor(csq, off);
    float cnorm = fmaxf(sqrtf(csq), 1e-8f);

    for (int j = wave; j < NN; j += 4) {
        int eid = conn[j * 2 + 1];
        const float* e = emb + (size_t)eid * D;
        float e0 = e[lane * 2], e1 = e[lane * 2 + 1];
        float dot = c0 * e0 + c1 * e1;
        float sq = e0 * e0 + e1 * e1;
        #pragma unroll
        for (int off = 32; off; off >>= 1) {
            dot += __shfl_xor(dot, off);
            sq  += __shfl_xor(sq, off);
        }
        if (lane == 0) sim[j] = dot / (cnorm * fmaxf(sqrtf(sq), 1e-8f));
    }
    __syncthreads();

    // top-10 by (max value, min index) — matches jax.lax.top_k tie-breaking
    if (wave == 0) {
        float s = sim[lane];
        int id = lane;
        for (int k = 0; k < KNN; k++) {
            float bs = s; int bi = id;
            #pragma unroll
            for (int off = 32; off; off >>= 1) {
                float os = __shfl_xor(bs, off);
                int   oi = __shfl_xor(bi, off);
                if (os > bs || (os == bs && oi < bi)) { bs = os; bi = oi; }
            }
            if (lane == 0) { selr[k] = conn[bi * 2]; sele[k] = conn[bi * 2 + 1]; }
            if (id == bi) s = -__builtin_inff();
        }
    }
    __syncthreads();

    float acc = 0.f;
    if (tid < D) {
        for (int k = 0; k < KNN; k++) acc += emb[(size_t)selr[k] * D + tid];
    } else {
        int d = tid - D;
        for (int k = 0; k < KNN; k++) acc += emb[(size_t)sele[k] * D + d];
    }
    catm[tid] = acc * (1.f / KNN);
    __syncthreads();

    int d = tid & (D - 1);
    int half = tid >> 7;
    const float4* W4  = (const float4*)(gcn_W + (size_t)d * (2 * D) + half * D);
    const float4* cm4 = (const float4*)(catm + half * D);
    float p = 0.f;
    #pragma unroll
    for (int f4 = 0; f4 < D / 4; ++f4) {
        float4 w = W4[f4]; float4 cv = cm4[f4];
        p += w.x * cv.x + w.y * cv.y + w.z * cv.z + w.w * cv.w;
    }
    pp[tid] = p;
    __syncthreads();
    if (tid < D) {
        float h = pp[tid] + pp[tid + D] + gcn_wb[tid] + gcn_b[tid];
        out[(size_t)row * (2 * D) + side * D + tid] = tanh_fast(h);
    }
}

// ---------------- support encoder (residual FFN + LayerNorm) ----------------
#define SE_ROWS 8
__global__ __launch_bounds__(256) void se_kernel(
    const float* __restrict__ x, const float* __restrict__ w1,
    const float* __restrict__ b1, const float* __restrict__ w2,
    const float* __restrict__ b2, const float* __restrict__ g,
    const float* __restrict__ b, float* __restrict__ out,
    ushort* __restrict__ out_bf)
{
    __shared__ float xs[SE_ROWS][DM];
    __shared__ float t1s[SE_ROWS][DI];
    __shared__ float ys[SE_ROWS][DM];
    int tid = threadIdx.x;
    int r0 = blockIdx.x * SE_ROWS;
    for (int r = 0; r < SE_ROWS; r++) xs[r][tid] = x[(size_t)(r0 + r) * DM + tid];
    __syncthreads();

    for (int jj = 0; jj < 2; ++jj) {
        int j = tid + jj * 256;
        float acc[SE_ROWS];
        #pragma unroll
        for (int r = 0; r < SE_ROWS; r++) acc[r] = 0.f;
        const float4* w4 = (const float4*)(w1 + (size_t)j * DM);
        for (int f4 = 0; f4 < DM / 4; ++f4) {
            float4 w = w4[f4];
            #pragma unroll
            for (int r = 0; r < SE_ROWS; r++) {
                const float* xr = &xs[r][f4 * 4];
                acc[r] += w.x * xr[0] + w.y * xr[1] + w.z * xr[2] + w.w * xr[3];
            }
        }
        float bj = b1[j];
        #pragma unroll
        for (int r = 0; r < SE_ROWS; r++) t1s[r][j] = fmaxf(acc[r] + bj, 0.f);
    }
    __syncthreads();

    {
        float acc[SE_ROWS];
        #pragma unroll
        for (int r = 0; r < SE_ROWS; r++) acc[r] = 0.f;
        const float4* w4 = (const float4*)(w2 + (size_t)tid * DI);
        for (int f4 = 0; f4 < DI / 4; ++f4) {
            float4 w = w4[f4];
            #pragma unroll
            for (int r = 0; r < SE_ROWS; r++) {
                const float* tr = &t1s[r][f4 * 4];
                acc[r] += w.x * tr[0] + w.y * tr[1] + w.z * tr[2] + w.w * tr[3];
            }
        }
        float bt = b2[tid];
        #pragma unroll
        for (int r = 0; r < SE_ROWS; r++) ys[r][tid] = acc[r] + bt + xs[r][tid];
    }
    __syncthreads();

    int wave = tid >> 6, lane = tid & 63;
    for (int rr = 0; rr < 2; ++rr) {
        int r = wave * 2 + rr;
        float s = 0.f;
        #pragma unroll
        for (int e = 0; e < 4; e++) s += ys[r][e * 64 + lane];
        #pragma unroll
        for (int off = 32; off; off >>= 1) s += __shfl_xor(s, off);
        float mu = s * (1.f / DM);
        float v = 0.f;
        #pragma unroll
        for (int e = 0; e < 4; e++) {
            float dd = ys[r][e * 64 + lane] - mu;
            v += dd * dd;
        }
        #pragma unroll
        for (int off = 32; off; off >>= 1) v += __shfl_xor(v, off);
        float rstd = rsqrtf(v * (1.f / DM) + 1e-5f);
        #pragma unroll
        for (int e = 0; e < 4; e++) {
            int dd = e * 64 + lane;
            float ov = (ys[r][dd] - mu) * rstd * g[dd] + b[dd];
            out[(size_t)(r0 + r) * DM + dd] = ov;
            if (out_bf) out_bf[(size_t)(r0 + r) * DM + dd] = f2bf(ov);
        }
    }
}

// ---------------- support_g = mean over BS rows ----------------
__global__ void sg_reduce_kernel(const float* __restrict__ se_s, float* __restrict__ sg)
{
    int tid = threadIdx.x;
    float a = 0.f;
    for (int r = 0; r < BS; r++) a += se_s[(size_t)r * DM + tid];
    sg[tid] = a * (1.f / BS);
}

// ------- per-gate constants: bsum = b_ih+b_hh ; gadd = bsum + sg@W_hh[:,256:].T -------
__global__ __launch_bounds__(256) void sgw_kernel(
    const float* __restrict__ W_hh, const float* __restrict__ sg,
    const float* __restrict__ b_ih, const float* __restrict__ b_hh,
    float* __restrict__ bsum, float* __restrict__ gadd)
{
    __shared__ float s[DM];
    int tid = threadIdx.x;
    s[tid] = sg[tid];
    __syncthreads();
    int g = blockIdx.x * 256 + tid;
    const float4* w4 = (const float4*)(W_hh + (size_t)g * HH + DM);
    float acc = 0.f;
    for (int f4 = 0; f4 < DM / 4; ++f4) {
        float4 w = w4[f4];
        acc += w.x * s[f4 * 4] + w.y * s[f4 * 4 + 1] + w.z * s[f4 * 4 + 2] + w.w * s[f4 * 4 + 3];
    }
    float bs = b_ih[g] + b_hh[g];
    bsum[g] = bs;
    gadd[g] = bs + acc;
}

// ---------------- weight conversion to bf16 ----------------
__global__ __launch_bounds__(256) void wcvt_kernel(
    const float* __restrict__ W_ih, const float* __restrict__ W_hh,
    ushort* __restrict__ wih_bf, ushort* __restrict__ whh_bf)
{
    int idx = blockIdx.x * 256 + threadIdx.x;   // 0 .. 2048*256-1
    int g = idx >> 8, j = idx & 255;
    wih_bf[idx] = f2bf(W_ih[idx]);
    whh_bf[idx] = f2bf(W_hh[(size_t)g * HH + j]);
}

// ---------------- bf16 MFMA GEMM: C[M,N] = A[M,K] * B[N,K]^T ----------------
// M=4096 (grid.x=32), N=2048 (grid.y=16), K=256.  128x128 block tile, BK=64.
#define BMT 128
#define BNT 128
#define BKT 64
#define LDP (BKT + 8)   // +8 ushorts = +16B pad: breaks 16-way ds_read bank aliasing to 2-way
__global__ __launch_bounds__(256) void gemm_bf16_kernel(
    const ushort* __restrict__ A, const ushort* __restrict__ B,
    float* __restrict__ C)
{
    __shared__ __align__(16) ushort As[BMT][LDP];
    __shared__ __align__(16) ushort Bs[BNT][LDP];
    int tid = threadIdx.x;
    int wave = tid >> 6, lane = tid & 63;
    int quad = lane >> 4, l16 = lane & 15;
    int bm = blockIdx.x, bn = blockIdx.y;
    int wm = (wave >> 1) * 64, wn = (wave & 1) * 64;

    floatx4 acc[4][4];
    #pragma unroll
    for (int i = 0; i < 4; i++)
        #pragma unroll
        for (int j = 0; j < 4; j++) acc[i][j] = (floatx4){0.f, 0.f, 0.f, 0.f};

    for (int k0 = 0; k0 < GK; k0 += BKT) {
        __syncthreads();
        #pragma unroll
        for (int t = 0; t < 4; t++) {
            int chunk = tid + 256 * t;          // 0..1023
            int r = chunk >> 3;                 // 0..127
            int c8 = (chunk & 7) * 8;           // 0,8,..,56
            *(uint4*)&As[r][c8] = *(const uint4*)&A[(size_t)(bm * BMT + r) * GK + k0 + c8];
            *(uint4*)&Bs[r][c8] = *(const uint4*)&B[(size_t)(bn * BNT + r) * GK + k0 + c8];
        }
        __syncthreads();
        #pragma unroll
        for (int kk = 0; kk < BKT; kk += 32) {
            bf16x8 af[4], bf[4];
            #pragma unroll
            for (int i = 0; i < 4; i++)
                af[i] = *(const bf16x8*)&As[wm + i * 16 + l16][kk + quad * 8];
            #pragma unroll
            for (int j = 0; j < 4; j++)
                bf[j] = *(const bf16x8*)&Bs[wn + j * 16 + l16][kk + quad * 8];
            #pragma unroll
            for (int i = 0; i < 4; i++)
                #pragma unroll
                for (int j = 0; j < 4; j++)
                    acc[i][j] = __builtin_amdgcn_mfma_f32_16x16x32_bf16(
                        af[i], bf[j], acc[i][j], 0, 0, 0);
        }
    }
    // C/D layout (verified m89/m91): col = lane&15, row = quad*4 + reg
    #pragma unroll
    for (int i = 0; i < 4; i++) {
        #pragma unroll
        for (int j = 0; j < 4; j++) {
            int row = bm * BMT + wm + i * 16 + quad * 4;
            int col = bn * BNT + wn + j * 16 + l16;
            #pragma unroll
            for (int rr = 0; rr < 4; rr++)
                C[(size_t)(row + rr) * GN + col] = acc[i][j][rr];
        }
    }
}

// ---------------- LSTM elementwise, step 1 (h_r = 0, c_prev = 0) ----------------
__global__ __launch_bounds__(256) void ew1_kernel(
    const float* __restrict__ P0, const float* __restrict__ bsum,
    const float* __restrict__ qg,
    float* __restrict__ c_ws, float* __restrict__ h_ws, ushort* __restrict__ h_bf)
{
    int row = blockIdx.x;
    const float* p = P0 + (size_t)row * G4;
    int tid = threadIdx.x;
    #pragma unroll
    for (int uu = 0; uu < 2; uu++) {
        int u = tid + uu * 256;
        float iv = p[u] + bsum[u];
        float gv = p[1024 + u] + bsum[1024 + u];
        float cv = sigmoidf_(iv) * tanh_fast(gv);
        c_ws[(size_t)row * HH + u] = cv;
        if (uu == 0) {
            float ov = p[1536 + u] + bsum[1536 + u];
            float hn = sigmoidf_(ov) * tanh_fast(cv);
            float h = qg[(size_t)row * DM + u] + hn;
            h_ws[(size_t)row * DM + u] = h;
            h_bf[(size_t)row * DM + u] = f2bf(h);
        }
    }
}

// ---------------- LSTM elementwise, steps 2..4 ----------------
__global__ __launch_bounds__(256) void ew_kernel(
    const float* __restrict__ P0, const float* __restrict__ P,
    const float* __restrict__ gadd, const float* __restrict__ qg,
    float* __restrict__ c_ws, float* __restrict__ h_ws, ushort* __restrict__ h_bf,
    int write_bf)
{
    int row = blockIdx.x;
    size_t b0 = (size_t)row * G4;
    int tid = threadIdx.x;
    #pragma unroll
    for (int uu = 0; uu < 2; uu++) {
        int u = tid + uu * 256;
        float iv = P0[b0 + u]        + P[b0 + u]        + gadd[u];
        float fv = P0[b0 + 512 + u]  + P[b0 + 512 + u]  + gadd[512 + u];
        float gv = P0[b0 + 1024 + u] + P[b0 + 1024 + u] + gadd[1024 + u];
        size_t cix = (size_t)row * HH + u;
        float cv = sigmoidf_(fv) * c_ws[cix] + sigmoidf_(iv) * tanh_fast(gv);
        c_ws[cix] = cv;
        if (uu == 0) {
            float ov = P0[b0 + 1536 + u] + P[b0 + 1536 + u] + gadd[1536 + u];
            float hn = sigmoidf_(ov) * tanh_fast(cv);
            float h = qg[(size_t)row * DM + u] + hn;
            h_ws[(size_t)row * DM + u] = h;
            if (write_bf) h_bf[(size_t)row * DM + u] = f2bf(h);
        }
    }
}

// ---------------- final cosine ----------------
__global__ __launch_bounds__(256) void final_kernel(
    const float* __restrict__ h_ws, const float* __restrict__ sg,
    float* __restrict__ outp)
{
    __shared__ float sgs[DM];
    int tid = threadIdx.x;
    sgs[tid] = sg[tid];
    __syncthreads();
    int wave = tid >> 6, lane = tid & 63;
    float sn = 0.f;
    #pragma unroll
    for (int e = 0; e < 4; e++) { float v = sgs[e * 64 + lane]; sn += v * v; }
    #pragma unroll
    for (int off = 32; off; off >>= 1) sn += __shfl_xor(sn, off);
    float sgnorm = fmaxf(sqrtf(sn), 1e-12f);

    int row = blockIdx.x * 4 + wave;
    const float* h = h_ws + (size_t)row * DM;
    float dot = 0.f, hn = 0.f;
    #pragma unroll
    for (int e = 0; e < 4; e++) {
        float hv = h[e * 64 + lane];
        dot += hv * sgs[e * 64 + lane];
        hn += hv * hv;
    }
    #pragma unroll
    for (int off = 32; off; off >>= 1) { dot += __shfl_xor(dot, off); hn += __shfl_xor(hn, off); }
    if (lane == 0) outp[row] = dot / (fmaxf(sqrtf(hn), 1e-12f) * sgnorm);
}

extern "C" void kernel_launch(void* const* d_in, const int* in_sizes, int n_in,
                              void* d_out, int out_size, void* d_ws, size_t ws_size,
                              hipStream_t stream)
{
    const int* query    = (const int*)d_in[0];
    const int* support  = (const int*)d_in[1];
    const int* q_l_conn = (const int*)d_in[2];
    const int* q_r_conn = (const int*)d_in[4];
    const int* s_l_conn = (const int*)d_in[6];
    const int* s_r_conn = (const int*)d_in[8];
    const float* emb    = (const float*)d_in[10];
    const float* gcn_W  = (const float*)d_in[11];
    const float* gcn_wb = (const float*)d_in[12];
    const float* gcn_b  = (const float*)d_in[13];
    const float* se_w1  = (const float*)d_in[14];
    const float* se_b1  = (const float*)d_in[15];
    const float* se_w2  = (const float*)d_in[16];
    const float* se_b2  = (const float*)d_in[17];
    const float* ln_g   = (const float*)d_in[18];
    const float* ln_b   = (const float*)d_in[19];
    const float* W_ih   = (const float*)d_in[20];
    const float* W_hh   = (const float*)d_in[21];
    const float* b_ih   = (const float*)d_in[22];
    const float* b_hh   = (const float*)d_in[23];
    float* out = (float*)d_out;

    char* wsb = (char*)d_ws;
    float*  q_nb   = (float*)wsb;  wsb += (size_t)BQ * DM * 4;
    float*  s_nb   = (float*)wsb;  wsb += (size_t)BS * DM * 4;
    float*  se_s   = (float*)wsb;  wsb += (size_t)BS * DM * 4;
    float*  sg     = (float*)wsb;  wsb += DM * 4;
    float*  qg     = (float*)wsb;  wsb += (size_t)BQ * DM * 4;
    ushort* qg_bf  = (ushort*)wsb; wsb += (size_t)BQ * DM * 2;
    float*  bsum   = (float*)wsb;  wsb += G4 * 4;
    float*  gadd   = (float*)wsb;  wsb += G4 * 4;
    ushort* wih_bf = (ushort*)wsb; wsb += (size_t)G4 * DM * 2;
    ushort* whh_bf = (ushort*)wsb; wsb += (size_t)G4 * DM * 2;
    float*  P0     = (float*)wsb;  wsb += (size_t)BQ * G4 * 4;
    float*  P      = (float*)wsb;  wsb += (size_t)BQ * G4 * 4;
    float*  h_ws   = (float*)wsb;  wsb += (size_t)BQ * DM * 4;
    ushort* h_bf   = (ushort*)wsb; wsb += (size_t)BQ * DM * 2;
    float*  c_ws   = (float*)wsb;  wsb += (size_t)BQ * HH * 4;

    wcvt_kernel<<<G4 * DM / 256, 256, 0, stream>>>(W_ih, W_hh, wih_bf, whh_bf);
    ne_kernel<<<BQ * 2, 256, 0, stream>>>(q_l_conn, q_r_conn, query, emb,
                                          gcn_W, gcn_wb, gcn_b, q_nb);
    ne_kernel<<<BS * 2, 256, 0, stream>>>(s_l_conn, s_r_conn, support, emb,
                                          gcn_W, gcn_wb, gcn_b, s_nb);
    se_kernel<<<BS / SE_ROWS, 256, 0, stream>>>(s_nb, se_w1, se_b1, se_w2, se_b2,
                                                ln_g, ln_b, se_s, (ushort*)nullptr);
    sg_reduce_kernel<<<1, 256, 0, stream>>>(se_s, sg);
    se_kernel<<<BQ / SE_ROWS, 256, 0, stream>>>(q_nb, se_w1, se_b1, se_w2, se_b2,
                                                ln_g, ln_b, qg, qg_bf);
    sgw_kernel<<<G4 / 256, 256, 0, stream>>>(W_hh, sg, b_ih, b_hh, bsum, gadd);

    dim3 ggrid(BQ / BMT, GN / BNT);
    gemm_bf16_kernel<<<ggrid, 256, 0, stream>>>(qg_bf, wih_bf, P0);
    ew1_kernel<<<BQ, 256, 0, stream>>>(P0, bsum, qg, c_ws, h_ws, h_bf);
    for (int s = 0; s < 3; s++) {
        gemm_bf16_kernel<<<ggrid, 256, 0, stream>>>(h_bf, whh_bf, P);
        ew_kernel<<<BQ, 256, 0, stream>>>(P0, P, gadd, qg, c_ws, h_ws, h_bf,
                                          (s < 2) ? 1 : 0);
    }
    final_kernel<<<BQ / 4, 256, 0, stream>>>(h_ws, sg, out);
}

// Round 3
// 614.209 us; speedup vs baseline: 2.5563x; 1.1530x over previous
//
#include <hip/hip_runtime.h>
#include <hip/hip_bf16.h>

#define D   128
#define DM  256
#define DI  512
#define HH  512
#define KNN 10
#define NN  64
#define BQ  4096
#define BS  128
#define G4  2048   // 4*HH
#define GN  2048   // GEMM N
#define GK  256    // GEMM K

__device__ __forceinline__ float sigmoidf_(float x) {
    return 1.f / (1.f + __expf(-x));
}
__device__ __forceinline__ float tanh_fast(float x) {
    x = fminf(fmaxf(x, -20.f), 20.f);
    float e = __expf(2.f * x);
    return (e - 1.f) / (e + 1.f);
}
__device__ __forceinline__ ushort f2bf(float x) {
    union { float f; unsigned u; } v; v.f = x;
    unsigned r = (v.u + 0x7fffu + ((v.u >> 16) & 1u)) >> 16;  // RNE
    return (ushort)r;
}

typedef __bf16  bf16x8  __attribute__((ext_vector_type(8)));
typedef float   floatx4 __attribute__((ext_vector_type(4)));

// ---------------- neighbor encoder: sims + top-k + concat-mean ----------------
// grid = B*2 blocks (row = bid>>1, side = bid&1). Writes catm[m=bid][256].
__global__ __launch_bounds__(256) void ne_kernel(
    const int* __restrict__ conn_l, const int* __restrict__ conn_r,
    const int* __restrict__ ids, const float* __restrict__ emb,
    float* __restrict__ catm_out)
{
    int row = blockIdx.x >> 1;
    int side = blockIdx.x & 1;
    const int* conn = (side ? conn_r : conn_l) + (size_t)row * NN * 2;
    int cid = ids[row * 2 + side];

    __shared__ float es[NN][D];       // 32 KB: all 64 ent rows (reused for mean)
    __shared__ float cen[D];
    __shared__ int   crel[NN], cent[NN];
    __shared__ float sim[NN];
    __shared__ int   selr[KNN], seli[KNN];

    int tid = threadIdx.x;
    int wave = tid >> 6, lane = tid & 63;

    if (tid < NN) { crel[tid] = conn[tid * 2]; cent[tid] = conn[tid * 2 + 1]; }
    if (tid >= 64 && tid < 96) {
        int c4 = tid - 64;
        *(float4*)&cen[c4 * 4] = *(const float4*)&emb[(size_t)cid * D + c4 * 4];
    }
    __syncthreads();

    // stage 64 rows: 8 independent float4 loads per thread (deep MLP)
    #pragma unroll
    for (int t = 0; t < 8; t++) {
        int chunk = tid + 256 * t;       // 0..2047
        int r = chunk >> 5;              // 0..63
        int c4 = chunk & 31;             // 0..31
        *(float4*)&es[r][c4 * 4] =
            *(const float4*)&emb[(size_t)cent[r] * D + c4 * 4];
    }
    __syncthreads();

    // sims from LDS — reduction order bit-identical to the verified version
    float c0 = cen[lane * 2], c1 = cen[lane * 2 + 1];
    float csq = c0 * c0 + c1 * c1;
    #pragma unroll
    for (int off = 32; off; off >>= 1) csq += __shfl_xor(csq, off);
    float cnorm = fmaxf(sqrtf(csq), 1e-8f);

    for (int j = wave; j < NN; j += 4) {
        float e0 = es[j][lane * 2], e1 = es[j][lane * 2 + 1];
        float dot = c0 * e0 + c1 * e1;
        float sq = e0 * e0 + e1 * e1;
        #pragma unroll
        for (int off = 32; off; off >>= 1) {
            dot += __shfl_xor(dot, off);
            sq  += __shfl_xor(sq, off);
        }
        if (lane == 0) sim[j] = dot / (cnorm * fmaxf(sqrtf(sq), 1e-8f));
    }
    __syncthreads();

    // top-10 by (max value, min index) — matches jax.lax.top_k tie-breaking
    if (wave == 0) {
        float s = sim[lane];
        int id = lane;
        for (int k = 0; k < KNN; k++) {
            float bs = s; int bi = id;
            #pragma unroll
            for (int off = 32; off; off >>= 1) {
                float os = __shfl_xor(bs, off);
                int   oi = __shfl_xor(bi, off);
                if (os > bs || (os == bs && oi < bi)) { bs = os; bi = oi; }
            }
            if (lane == 0) { selr[k] = crel[bi]; seli[k] = bi; }
            if (id == bi) s = -__builtin_inff();
        }
    }
    __syncthreads();

    // concat-mean: rel half gathered from global (10 independent coalesced rows),
    // ent half re-used from LDS
    float acc = 0.f;
    if (tid < D) {
        #pragma unroll
        for (int k = 0; k < KNN; k++) acc += emb[(size_t)selr[k] * D + tid];
    } else {
        int d = tid - D;
        #pragma unroll
        for (int k = 0; k < KNN; k++) acc += es[seli[k]][d];
    }
    catm_out[(size_t)blockIdx.x * DM + tid] = acc * (1.f / KNN);
}

// ---------------- batched GCN transform: out[m,d] = tanh(catm[m,:] @ W[d,:] + b) ----------------
#define GR 16
__global__ __launch_bounds__(256) void gcn_kernel(
    const float* __restrict__ catm, const float* __restrict__ gcn_W,
    const float* __restrict__ gcn_wb, const float* __restrict__ gcn_b,
    float* __restrict__ out)
{
    __shared__ float cs[GR][DM];   // 16 KB
    __shared__ float pp[GR][DM];   // 16 KB
    int tid = threadIdx.x;
    int m0 = blockIdx.x * GR;
    #pragma unroll
    for (int t = 0; t < 4; t++) {
        int chunk = tid + 256 * t;   // 0..1023
        int r = chunk >> 6, c4 = chunk & 63;
        *(float4*)&cs[r][c4 * 4] = *(const float4*)&catm[(size_t)(m0 + r) * DM + c4 * 4];
    }
    __syncthreads();

    int d = tid & 127, half = tid >> 7;
    float a[GR];
    #pragma unroll
    for (int r = 0; r < GR; r++) a[r] = 0.f;
    const float4* W4 = (const float4*)(gcn_W + (size_t)d * DM + half * D);
    for (int f4 = 0; f4 < D / 4; ++f4) {
        float4 w = W4[f4];
        #pragma unroll
        for (int r = 0; r < GR; r++) {
            const float* c = &cs[r][half * D + f4 * 4];   // wave-broadcast LDS read
            a[r] += w.x * c[0] + w.y * c[1] + w.z * c[2] + w.w * c[3];
        }
    }
    #pragma unroll
    for (int r = 0; r < GR; r++) pp[r][tid] = a[r];
    __syncthreads();
    if (tid < D) {
        #pragma unroll
        for (int r = 0; r < GR; r++) {
            float h = pp[r][tid] + pp[r][tid + D] + gcn_wb[tid] + gcn_b[tid];
            out[(size_t)(m0 + r) * D + tid] = tanh_fast(h);
        }
    }
}

// ---------------- support encoder (residual FFN + LayerNorm) ----------------
#define SE_ROWS 8
__global__ __launch_bounds__(256) void se_kernel(
    const float* __restrict__ x, const float* __restrict__ w1,
    const float* __restrict__ b1, const float* __restrict__ w2,
    const float* __restrict__ b2, const float* __restrict__ g,
    const float* __restrict__ b, float* __restrict__ out,
    ushort* __restrict__ out_bf)
{
    __shared__ float xs[SE_ROWS][DM];
    __shared__ float t1s[SE_ROWS][DI];
    __shared__ float ys[SE_ROWS][DM];
    int tid = threadIdx.x;
    int r0 = blockIdx.x * SE_ROWS;
    for (int r = 0; r < SE_ROWS; r++) xs[r][tid] = x[(size_t)(r0 + r) * DM + tid];
    __syncthreads();

    for (int jj = 0; jj < 2; ++jj) {
        int j = tid + jj * 256;
        float acc[SE_ROWS];
        #pragma unroll
        for (int r = 0; r < SE_ROWS; r++) acc[r] = 0.f;
        const float4* w4 = (const float4*)(w1 + (size_t)j * DM);
        for (int f4 = 0; f4 < DM / 4; ++f4) {
            float4 w = w4[f4];
            #pragma unroll
            for (int r = 0; r < SE_ROWS; r++) {
                const float* xr = &xs[r][f4 * 4];
                acc[r] += w.x * xr[0] + w.y * xr[1] + w.z * xr[2] + w.w * xr[3];
            }
        }
        float bj = b1[j];
        #pragma unroll
        for (int r = 0; r < SE_ROWS; r++) t1s[r][j] = fmaxf(acc[r] + bj, 0.f);
    }
    __syncthreads();

    {
        float acc[SE_ROWS];
        #pragma unroll
        for (int r = 0; r < SE_ROWS; r++) acc[r] = 0.f;
        const float4* w4 = (const float4*)(w2 + (size_t)tid * DI);
        for (int f4 = 0; f4 < DI / 4; ++f4) {
            float4 w = w4[f4];
            #pragma unroll
            for (int r = 0; r < SE_ROWS; r++) {
                const float* tr = &t1s[r][f4 * 4];
                acc[r] += w.x * tr[0] + w.y * tr[1] + w.z * tr[2] + w.w * tr[3];
            }
        }
        float bt = b2[tid];
        #pragma unroll
        for (int r = 0; r < SE_ROWS; r++) ys[r][tid] = acc[r] + bt + xs[r][tid];
    }
    __syncthreads();

    int wave = tid >> 6, lane = tid & 63;
    for (int rr = 0; rr < 2; ++rr) {
        int r = wave * 2 + rr;
        float s = 0.f;
        #pragma unroll
        for (int e = 0; e < 4; e++) s += ys[r][e * 64 + lane];
        #pragma unroll
        for (int off = 32; off; off >>= 1) s += __shfl_xor(s, off);
        float mu = s * (1.f / DM);
        float v = 0.f;
        #pragma unroll
        for (int e = 0; e < 4; e++) {
            float dd = ys[r][e * 64 + lane] - mu;
            v += dd * dd;
        }
        #pragma unroll
        for (int off = 32; off; off >>= 1) v += __shfl_xor(v, off);
        float rstd = rsqrtf(v * (1.f / DM) + 1e-5f);
        #pragma unroll
        for (int e = 0; e < 4; e++) {
            int dd = e * 64 + lane;
            float ov = (ys[r][dd] - mu) * rstd * g[dd] + b[dd];
            out[(size_t)(r0 + r) * DM + dd] = ov;
            if (out_bf) out_bf[(size_t)(r0 + r) * DM + dd] = f2bf(ov);
        }
    }
}

// ---------------- support_g = mean over BS rows ----------------
__global__ void sg_reduce_kernel(const float* __restrict__ se_s, float* __restrict__ sg)
{
    int tid = threadIdx.x;
    float a = 0.f;
    for (int r = 0; r < BS; r++) a += se_s[(size_t)r * DM + tid];
    sg[tid] = a * (1.f / BS);
}

// ------- per-gate constants: bsum = b_ih+b_hh ; gadd = bsum + sg@W_hh[:,256:].T -------
__global__ __launch_bounds__(256) void sgw_kernel(
    const float* __restrict__ W_hh, const float* __restrict__ sg,
    const float* __restrict__ b_ih, const float* __restrict__ b_hh,
    float* __restrict__ bsum, float* __restrict__ gadd)
{
    __shared__ float s[DM];
    int tid = threadIdx.x;
    s[tid] = sg[tid];
    __syncthreads();
    int g = blockIdx.x * 256 + tid;
    const float4* w4 = (const float4*)(W_hh + (size_t)g * HH + DM);
    float acc = 0.f;
    for (int f4 = 0; f4 < DM / 4; ++f4) {
        float4 w = w4[f4];
        acc += w.x * s[f4 * 4] + w.y * s[f4 * 4 + 1] + w.z * s[f4 * 4 + 2] + w.w * s[f4 * 4 + 3];
    }
    float bs = b_ih[g] + b_hh[g];
    bsum[g] = bs;
    gadd[g] = bs + acc;
}

// ---------------- weight conversion to bf16 ----------------
__global__ __launch_bounds__(256) void wcvt_kernel(
    const float* __restrict__ W_ih, const float* __restrict__ W_hh,
    ushort* __restrict__ wih_bf, ushort* __restrict__ whh_bf)
{
    int idx = blockIdx.x * 256 + threadIdx.x;   // 0 .. 2048*256-1
    int g = idx >> 8, j = idx & 255;
    wih_bf[idx] = f2bf(W_ih[idx]);
    whh_bf[idx] = f2bf(W_hh[(size_t)g * HH + j]);
}

// ---------------- bf16 MFMA GEMM: C[M,N] = A[M,K] * B[N,K]^T ----------------
#define BMT 128
#define BNT 128
#define BKT 64
#define LDP (BKT + 8)
__global__ __launch_bounds__(256) void gemm_bf16_kernel(
    const ushort* __restrict__ A, const ushort* __restrict__ B,
    float* __restrict__ C)
{
    __shared__ __align__(16) ushort As[BMT][LDP];
    __shared__ __align__(16) ushort Bs[BNT][LDP];
    int tid = threadIdx.x;
    int wave = tid >> 6, lane = tid & 63;
    int quad = lane >> 4, l16 = lane & 15;
    int bm = blockIdx.x, bn = blockIdx.y;
    int wm = (wave >> 1) * 64, wn = (wave & 1) * 64;

    floatx4 acc[4][4];
    #pragma unroll
    for (int i = 0; i < 4; i++)
        #pragma unroll
        for (int j = 0; j < 4; j++) acc[i][j] = (floatx4){0.f, 0.f, 0.f, 0.f};

    for (int k0 = 0; k0 < GK; k0 += BKT) {
        __syncthreads();
        #pragma unroll
        for (int t = 0; t < 4; t++) {
            int chunk = tid + 256 * t;
            int r = chunk >> 3;
            int c8 = (chunk & 7) * 8;
            *(uint4*)&As[r][c8] = *(const uint4*)&A[(size_t)(bm * BMT + r) * GK + k0 + c8];
            *(uint4*)&Bs[r][c8] = *(const uint4*)&B[(size_t)(bn * BNT + r) * GK + k0 + c8];
        }
        __syncthreads();
        #pragma unroll
        for (int kk = 0; kk < BKT; kk += 32) {
            bf16x8 af[4], bf[4];
            #pragma unroll
            for (int i = 0; i < 4; i++)
                af[i] = *(const bf16x8*)&As[wm + i * 16 + l16][kk + quad * 8];
            #pragma unroll
            for (int j = 0; j < 4; j++)
                bf[j] = *(const bf16x8*)&Bs[wn + j * 16 + l16][kk + quad * 8];
            #pragma unroll
            for (int i = 0; i < 4; i++)
                #pragma unroll
                for (int j = 0; j < 4; j++)
                    acc[i][j] = __builtin_amdgcn_mfma_f32_16x16x32_bf16(
                        af[i], bf[j], acc[i][j], 0, 0, 0);
        }
    }
    #pragma unroll
    for (int i = 0; i < 4; i++) {
        #pragma unroll
        for (int j = 0; j < 4; j++) {
            int row = bm * BMT + wm + i * 16 + quad * 4;
            int col = bn * BNT + wn + j * 16 + l16;
            #pragma unroll
            for (int rr = 0; rr < 4; rr++)
                C[(size_t)(row + rr) * GN + col] = acc[i][j][rr];
        }
    }
}

// ---------------- LSTM elementwise, step 1 (h_r = 0, c_prev = 0) ----------------
__global__ __launch_bounds__(256) void ew1_kernel(
    const float* __restrict__ P0, const float* __restrict__ bsum,
    const float* __restrict__ qg,
    float* __restrict__ c_ws, float* __restrict__ h_ws, ushort* __restrict__ h_bf)
{
    int row = blockIdx.x;
    const float* p = P0 + (size_t)row * G4;
    int tid = threadIdx.x;
    #pragma unroll
    for (int uu = 0; uu < 2; uu++) {
        int u = tid + uu * 256;
        float iv = p[u] + bsum[u];
        float gv = p[1024 + u] + bsum[1024 + u];
        float cv = sigmoidf_(iv) * tanh_fast(gv);
        c_ws[(size_t)row * HH + u] = cv;
        if (uu == 0) {
            float ov = p[1536 + u] + bsum[1536 + u];
            float hn = sigmoidf_(ov) * tanh_fast(cv);
            float h = qg[(size_t)row * DM + u] + hn;
            h_ws[(size_t)row * DM + u] = h;
            h_bf[(size_t)row * DM + u] = f2bf(h);
        }
    }
}

// ---------------- LSTM elementwise, steps 2..4 ----------------
__global__ __launch_bounds__(256) void ew_kernel(
    const float* __restrict__ P0, const float* __restrict__ P,
    const float* __restrict__ gadd, const float* __restrict__ qg,
    float* __restrict__ c_ws, float* __restrict__ h_ws, ushort* __restrict__ h_bf,
    int write_bf)
{
    int row = blockIdx.x;
    size_t b0 = (size_t)row * G4;
    int tid = threadIdx.x;
    #pragma unroll
    for (int uu = 0; uu < 2; uu++) {
        int u = tid + uu * 256;
        float iv = P0[b0 + u]        + P[b0 + u]        + gadd[u];
        float fv = P0[b0 + 512 + u]  + P[b0 + 512 + u]  + gadd[512 + u];
        float gv = P0[b0 + 1024 + u] + P[b0 + 1024 + u] + gadd[1024 + u];
        size_t cix = (size_t)row * HH + u;
        float cv = sigmoidf_(fv) * c_ws[cix] + sigmoidf_(iv) * tanh_fast(gv);
        c_ws[cix] = cv;
        if (uu == 0) {
            float ov = P0[b0 + 1536 + u] + P[b0 + 1536 + u] + gadd[1536 + u];
            float hn = sigmoidf_(ov) * tanh_fast(cv);
            float h = qg[(size_t)row * DM + u] + hn;
            h_ws[(size_t)row * DM + u] = h;
            if (write_bf) h_bf[(size_t)row * DM + u] = f2bf(h);
        }
    }
}

// ---------------- final cosine ----------------
__global__ __launch_bounds__(256) void final_kernel(
    const float* __restrict__ h_ws, const float* __restrict__ sg,
    float* __restrict__ outp)
{
    __shared__ float sgs[DM];
    int tid = threadIdx.x;
    sgs[tid] = sg[tid];
    __syncthreads();
    int wave = tid >> 6, lane = tid & 63;
    float sn = 0.f;
    #pragma unroll
    for (int e = 0; e < 4; e++) { float v = sgs[e * 64 + lane]; sn += v * v; }
    #pragma unroll
    for (int off = 32; off; off >>= 1) sn += __shfl_xor(sn, off);
    float sgnorm = fmaxf(sqrtf(sn), 1e-12f);

    int row = blockIdx.x * 4 + wave;
    const float* h = h_ws + (size_t)row * DM;
    float dot = 0.f, hn = 0.f;
    #pragma unroll
    for (int e = 0; e < 4; e++) {
        float hv = h[e * 64 + lane];
        dot += hv * sgs[e * 64 + lane];
        hn += hv * hv;
    }
    #pragma unroll
    for (int off = 32; off; off >>= 1) { dot += __shfl_xor(dot, off); hn += __shfl_xor(hn, off); }
    if (lane == 0) outp[row] = dot / (fmaxf(sqrtf(hn), 1e-12f) * sgnorm);
}

extern "C" void kernel_launch(void* const* d_in, const int* in_sizes, int n_in,
                              void* d_out, int out_size, void* d_ws, size_t ws_size,
                              hipStream_t stream)
{
    const int* query    = (const int*)d_in[0];
    const int* support  = (const int*)d_in[1];
    const int* q_l_conn = (const int*)d_in[2];
    const int* q_r_conn = (const int*)d_in[4];
    const int* s_l_conn = (const int*)d_in[6];
    const int* s_r_conn = (const int*)d_in[8];
    const float* emb    = (const float*)d_in[10];
    const float* gcn_W  = (const float*)d_in[11];
    const float* gcn_wb = (const float*)d_in[12];
    const float* gcn_b  = (const float*)d_in[13];
    const float* se_w1  = (const float*)d_in[14];
    const float* se_b1  = (const float*)d_in[15];
    const float* se_w2  = (const float*)d_in[16];
    const float* se_b2  = (const float*)d_in[17];
    const float* ln_g   = (const float*)d_in[18];
    const float* ln_b   = (const float*)d_in[19];
    const float* W_ih   = (const float*)d_in[20];
    const float* W_hh   = (const float*)d_in[21];
    const float* b_ih   = (const float*)d_in[22];
    const float* b_hh   = (const float*)d_in[23];
    float* out = (float*)d_out;

    char* wsb = (char*)d_ws;
    float*  q_nb   = (float*)wsb;  wsb += (size_t)BQ * DM * 4;   // s_nb must follow
    float*  s_nb   = (float*)wsb;  wsb += (size_t)BS * DM * 4;
    float*  se_s   = (float*)wsb;  wsb += (size_t)BS * DM * 4;
    float*  sg     = (float*)wsb;  wsb += DM * 4;
    float*  qg     = (float*)wsb;  wsb += (size_t)BQ * DM * 4;
    ushort* qg_bf  = (ushort*)wsb; wsb += (size_t)BQ * DM * 2;
    float*  bsum   = (float*)wsb;  wsb += G4 * 4;
    float*  gadd   = (float*)wsb;  wsb += G4 * 4;
    ushort* wih_bf = (ushort*)wsb; wsb += (size_t)G4 * DM * 2;
    ushort* whh_bf = (ushort*)wsb; wsb += (size_t)G4 * DM * 2;
    float*  P0     = (float*)wsb;  wsb += (size_t)BQ * G4 * 4;
    float*  P      = (float*)wsb;  wsb += (size_t)BQ * G4 * 4;
    float*  h_ws   = (float*)wsb;  wsb += (size_t)BQ * DM * 4;
    ushort* h_bf   = (ushort*)wsb; wsb += (size_t)BQ * DM * 2;
    float*  c_ws   = (float*)wsb;  wsb += (size_t)BQ * HH * 4;

    // catm [8448][256] aliases the P0 region (dead before first GEMM writes P0)
    float* catm = P0;

    wcvt_kernel<<<G4 * DM / 256, 256, 0, stream>>>(W_ih, W_hh, wih_bf, whh_bf);
    ne_kernel<<<BQ * 2, 256, 0, stream>>>(q_l_conn, q_r_conn, query, emb, catm);
    ne_kernel<<<BS * 2, 256, 0, stream>>>(s_l_conn, s_r_conn, support, emb,
                                          catm + (size_t)BQ * 2 * DM);
    // one batched GCN transform over all 8448 (row,side) pairs;
    // out[m*128+d] lands exactly on q_nb[4096][256] ++ s_nb[128][256]
    gcn_kernel<<<(BQ * 2 + BS * 2) / GR, 256, 0, stream>>>(catm, gcn_W, gcn_wb,
                                                           gcn_b, q_nb);
    se_kernel<<<BS / SE_ROWS, 256, 0, stream>>>(s_nb, se_w1, se_b1, se_w2, se_b2,
                                                ln_g, ln_b, se_s, (ushort*)nullptr);
    sg_reduce_kernel<<<1, 256, 0, stream>>>(se_s, sg);
    se_kernel<<<BQ / SE_ROWS, 256, 0, stream>>>(q_nb, se_w1, se_b1, se_w2, se_b2,
                                                ln_g, ln_b, qg, qg_bf);
    sgw_kernel<<<G4 / 256, 256, 0, stream>>>(W_hh, sg, b_ih, b_hh, bsum, gadd);

    dim3 ggrid(BQ / BMT, GN / BNT);
    gemm_bf16_kernel<<<ggrid, 256, 0, stream>>>(qg_bf, wih_bf, P0);
    ew1_kernel<<<BQ, 256, 0, stream>>>(P0, bsum, qg, c_ws, h_ws, h_bf);
    for (int s = 0; s < 3; s++) {
        gemm_bf16_kernel<<<ggrid, 256, 0, stream>>>(h_bf, whh_bf, P);
        ew_kernel<<<BQ, 256, 0, stream>>>(P0, P, gadd, qg, c_ws, h_ws, h_bf,
                                          (s < 2) ? 1 : 0);
    }
    final_kernel<<<BQ / 4, 256, 0, stream>>>(h_ws, sg, out);
}

// Round 4
// 462.347 us; speedup vs baseline: 3.3959x; 1.3285x over previous
//
#include <hip/hip_runtime.h>
#include <hip/hip_bf16.h>

#define D   128
#define DM  256
#define DI  512
#define HH  512
#define KNN 10
#define NN  64
#define BQ  4096
#define BS  128
#define BM2 (BQ + BS)        // 4224 batched se rows
#define G4  2048             // 4*HH
#define GN  2048             // LSTM GEMM N
#define GK  256              // LSTM GEMM K

__device__ __forceinline__ float sigmoidf_(float x) {
    return 1.f / (1.f + __expf(-x));
}
__device__ __forceinline__ float tanh_fast(float x) {
    x = fminf(fmaxf(x, -20.f), 20.f);
    float e = __expf(2.f * x);
    return (e - 1.f) / (e + 1.f);
}
__device__ __forceinline__ ushort f2bf(float x) {
    union { float f; unsigned u; } v; v.f = x;
    unsigned r = (v.u + 0x7fffu + ((v.u >> 16) & 1u)) >> 16;  // RNE
    return (ushort)r;
}

typedef __bf16  bf16x8  __attribute__((ext_vector_type(8)));
typedef float   floatx4 __attribute__((ext_vector_type(4)));

// ---------------- neighbor encoder: register-fragment version ----------------
// grid = B*2 blocks (row = bid>>1, side = bid&1). Writes catm[m=bid][256].
// Wave w owns neighbors j = 16w..16w+15; lane l holds dims 2l,2l+1 in regs.
__global__ __launch_bounds__(256) void ne_kernel(
    const int* __restrict__ conn_l, const int* __restrict__ conn_r,
    const int* __restrict__ ids, const float* __restrict__ emb,
    float* __restrict__ catm_out)
{
    int row = blockIdx.x >> 1;
    int side = blockIdx.x & 1;
    const int* conn = (side ? conn_r : conn_l) + (size_t)row * NN * 2;
    int cid = ids[row * 2 + side];

    __shared__ int   connb[NN * 2];   // [2j]=rel, [2j+1]=ent
    __shared__ float sim[NN];
    __shared__ int   selr[KNN], sele[KNN];

    int tid = threadIdx.x;
    int wave = tid >> 6, lane = tid & 63;

    if (tid < NN * 2) connb[tid] = conn[tid];
    // center fragment straight to regs (same row broadcast across waves)
    float2 c01 = *(const float2*)&emb[(size_t)cid * D + lane * 2];
    float c0 = c01.x, c1 = c01.y;
    float csq = c0 * c0 + c1 * c1;
    #pragma unroll
    for (int off = 32; off; off >>= 1) csq += __shfl_xor(csq, off);
    float cnorm = fmaxf(sqrtf(csq), 1e-8f);
    __syncthreads();

    // 16 independent 8B gathers per thread (deep MLP), fragments in VGPRs
    int cj[16];
    #pragma unroll
    for (int t = 0; t < 16; t++) cj[t] = connb[(wave * 16 + t) * 2 + 1];
    float2 ef[16];
    #pragma unroll
    for (int t = 0; t < 16; t++)
        ef[t] = *(const float2*)&emb[(size_t)cj[t] * D + lane * 2];

    // sims — per-j sum order bit-identical to the verified version
    #pragma unroll
    for (int t = 0; t < 16; t++) {
        float e0 = ef[t].x, e1 = ef[t].y;
        float dot = c0 * e0 + c1 * e1;
        float sq = e0 * e0 + e1 * e1;
        #pragma unroll
        for (int off = 32; off; off >>= 1) {
            dot += __shfl_xor(dot, off);
            sq  += __shfl_xor(sq, off);
        }
        if (lane == 0) sim[wave * 16 + t] = dot / (cnorm * fmaxf(sqrtf(sq), 1e-8f));
    }
    __syncthreads();

    // top-10 by (max value, min index) — matches jax.lax.top_k tie-breaking
    if (wave == 0) {
        float s = sim[lane];
        int id = lane;
        for (int k = 0; k < KNN; k++) {
            float bs = s; int bi = id;
            #pragma unroll
            for (int off = 32; off; off >>= 1) {
                float os = __shfl_xor(bs, off);
                int   oi = __shfl_xor(bi, off);
                if (os > bs || (os == bs && oi < bi)) { bs = os; bi = oi; }
            }
            if (lane == 0) { selr[k] = connb[bi * 2]; sele[k] = connb[bi * 2 + 1]; }
            if (id == bi) s = -__builtin_inff();
        }
    }
    __syncthreads();

    // concat-mean: both halves gathered from global (top rows are L2-hot)
    float acc = 0.f;
    if (tid < D) {
        #pragma unroll
        for (int k = 0; k < KNN; k++) acc += emb[(size_t)selr[k] * D + tid];
    } else {
        int d = tid - D;
        #pragma unroll
        for (int k = 0; k < KNN; k++) acc += emb[(size_t)sele[k] * D + d];
    }
    catm_out[(size_t)blockIdx.x * DM + tid] = acc * (1.f / KNN);
}

// ---------------- batched GCN transform: out[m,d] = tanh(catm[m,:] @ W[d,:] + b) ----------------
#define GR 16
__global__ __launch_bounds__(256) void gcn_kernel(
    const float* __restrict__ catm, const float* __restrict__ gcn_W,
    const float* __restrict__ gcn_wb, const float* __restrict__ gcn_b,
    float* __restrict__ out, ushort* __restrict__ out_bf)
{
    __shared__ float cs[GR][DM];
    __shared__ float pp[GR][DM];
    int tid = threadIdx.x;
    int m0 = blockIdx.x * GR;
    #pragma unroll
    for (int t = 0; t < 4; t++) {
        int chunk = tid + 256 * t;
        int r = chunk >> 6, c4 = chunk & 63;
        *(float4*)&cs[r][c4 * 4] = *(const float4*)&catm[(size_t)(m0 + r) * DM + c4 * 4];
    }
    __syncthreads();

    int d = tid & 127, half = tid >> 7;
    float a[GR];
    #pragma unroll
    for (int r = 0; r < GR; r++) a[r] = 0.f;
    const float4* W4 = (const float4*)(gcn_W + (size_t)d * DM + half * D);
    for (int f4 = 0; f4 < D / 4; ++f4) {
        float4 w = W4[f4];
        #pragma unroll
        for (int r = 0; r < GR; r++) {
            const float* c = &cs[r][half * D + f4 * 4];
            a[r] += w.x * c[0] + w.y * c[1] + w.z * c[2] + w.w * c[3];
        }
    }
    #pragma unroll
    for (int r = 0; r < GR; r++) pp[r][tid] = a[r];
    __syncthreads();
    if (tid < D) {
        #pragma unroll
        for (int r = 0; r < GR; r++) {
            float h = pp[r][tid] + pp[r][tid + D] + gcn_wb[tid] + gcn_b[tid];
            float th = tanh_fast(h);
            out[(size_t)(m0 + r) * D + tid] = th;
            out_bf[(size_t)(m0 + r) * D + tid] = f2bf(th);
        }
    }
}

// ---------------- weight conversion to bf16 ----------------
__global__ __launch_bounds__(256) void wcvt_kernel(
    const float* __restrict__ W_ih, const float* __restrict__ W_hh,
    const float* __restrict__ se_w1, const float* __restrict__ se_w2,
    ushort* __restrict__ wih_bf, ushort* __restrict__ whh_bf,
    ushort* __restrict__ w1_bf, ushort* __restrict__ w2_bf)
{
    int idx = blockIdx.x * 256 + threadIdx.x;   // 0 .. 2048*256-1
    int g = idx >> 8, j = idx & 255;
    wih_bf[idx] = f2bf(W_ih[idx]);
    whh_bf[idx] = f2bf(W_hh[(size_t)g * HH + j]);
    if (idx < DI * DM) {
        w1_bf[idx] = f2bf(se_w1[idx]);
        w2_bf[idx] = f2bf(se_w2[idx]);
    }
}

// ---------------- bf16 MFMA GEMM core (128x128 tile) ----------------
#define BMT 128
#define BNT 128
#define BKT 64
#define LDP (BKT + 8)

// LSTM GEMM: C[M,2048] = A[M,256] * B[2048,256]^T, fp32 C
__global__ __launch_bounds__(256) void gemm_bf16_kernel(
    const ushort* __restrict__ A, const ushort* __restrict__ B,
    float* __restrict__ C)
{
    __shared__ __align__(16) ushort As[BMT][LDP];
    __shared__ __align__(16) ushort Bs[BNT][LDP];
    int tid = threadIdx.x;
    int wave = tid >> 6, lane = tid & 63;
    int quad = lane >> 4, l16 = lane & 15;
    int bm = blockIdx.x, bn = blockIdx.y;
    int wm = (wave >> 1) * 64, wn = (wave & 1) * 64;

    floatx4 acc[4][4];
    #pragma unroll
    for (int i = 0; i < 4; i++)
        #pragma unroll
        for (int j = 0; j < 4; j++) acc[i][j] = (floatx4){0.f, 0.f, 0.f, 0.f};

    for (int k0 = 0; k0 < GK; k0 += BKT) {
        __syncthreads();
        #pragma unroll
        for (int t = 0; t < 4; t++) {
            int chunk = tid + 256 * t;
            int r = chunk >> 3;
            int c8 = (chunk & 7) * 8;
            *(uint4*)&As[r][c8] = *(const uint4*)&A[(size_t)(bm * BMT + r) * GK + k0 + c8];
            *(uint4*)&Bs[r][c8] = *(const uint4*)&B[(size_t)(bn * BNT + r) * GK + k0 + c8];
        }
        __syncthreads();
        #pragma unroll
        for (int kk = 0; kk < BKT; kk += 32) {
            bf16x8 af[4], bf[4];
            #pragma unroll
            for (int i = 0; i < 4; i++)
                af[i] = *(const bf16x8*)&As[wm + i * 16 + l16][kk + quad * 8];
            #pragma unroll
            for (int j = 0; j < 4; j++)
                bf[j] = *(const bf16x8*)&Bs[wn + j * 16 + l16][kk + quad * 8];
            #pragma unroll
            for (int i = 0; i < 4; i++)
                #pragma unroll
                for (int j = 0; j < 4; j++)
                    acc[i][j] = __builtin_amdgcn_mfma_f32_16x16x32_bf16(
                        af[i], bf[j], acc[i][j], 0, 0, 0);
        }
    }
    #pragma unroll
    for (int i = 0; i < 4; i++) {
        #pragma unroll
        for (int j = 0; j < 4; j++) {
            int row = bm * BMT + wm + i * 16 + quad * 4;
            int col = bn * BNT + wn + j * 16 + l16;
            #pragma unroll
            for (int rr = 0; rr < 4; rr++)
                C[(size_t)(row + rr) * GN + col] = acc[i][j][rr];
        }
    }
}

// se GEMM1: t1[M,512] = relu(x[M,256] @ w1[512,256]^T + b1), bf16 out
__global__ __launch_bounds__(256) void se_gemm1_kernel(
    const ushort* __restrict__ A, const ushort* __restrict__ B,
    const float* __restrict__ b1, ushort* __restrict__ Cbf)
{
    __shared__ __align__(16) ushort As[BMT][LDP];
    __shared__ __align__(16) ushort Bs[BNT][LDP];
    int tid = threadIdx.x;
    int wave = tid >> 6, lane = tid & 63;
    int quad = lane >> 4, l16 = lane & 15;
    int bm = blockIdx.x, bn = blockIdx.y;
    int wm = (wave >> 1) * 64, wn = (wave & 1) * 64;

    floatx4 acc[4][4];
    #pragma unroll
    for (int i = 0; i < 4; i++)
        #pragma unroll
        for (int j = 0; j < 4; j++) acc[i][j] = (floatx4){0.f, 0.f, 0.f, 0.f};

    for (int k0 = 0; k0 < DM; k0 += BKT) {
        __syncthreads();
        #pragma unroll
        for (int t = 0; t < 4; t++) {
            int chunk = tid + 256 * t;
            int r = chunk >> 3;
            int c8 = (chunk & 7) * 8;
            *(uint4*)&As[r][c8] = *(const uint4*)&A[(size_t)(bm * BMT + r) * DM + k0 + c8];
            *(uint4*)&Bs[r][c8] = *(const uint4*)&B[(size_t)(bn * BNT + r) * DM + k0 + c8];
        }
        __syncthreads();
        #pragma unroll
        for (int kk = 0; kk < BKT; kk += 32) {
            bf16x8 af[4], bf[4];
            #pragma unroll
            for (int i = 0; i < 4; i++)
                af[i] = *(const bf16x8*)&As[wm + i * 16 + l16][kk + quad * 8];
            #pragma unroll
            for (int j = 0; j < 4; j++)
                bf[j] = *(const bf16x8*)&Bs[wn + j * 16 + l16][kk + quad * 8];
            #pragma unroll
            for (int i = 0; i < 4; i++)
                #pragma unroll
                for (int j = 0; j < 4; j++)
                    acc[i][j] = __builtin_amdgcn_mfma_f32_16x16x32_bf16(
                        af[i], bf[j], acc[i][j], 0, 0, 0);
        }
    }
    #pragma unroll
    for (int i = 0; i < 4; i++) {
        #pragma unroll
        for (int j = 0; j < 4; j++) {
            int row = bm * BMT + wm + i * 16 + quad * 4;
            int col = bn * BNT + wn + j * 16 + l16;
            float bb = b1[col];
            #pragma unroll
            for (int rr = 0; rr < 4; rr++)
                Cbf[(size_t)(row + rr) * DI + col] = f2bf(fmaxf(acc[i][j][rr] + bb, 0.f));
        }
    }
}

// se GEMM2: y[M,256] = t1[M,512] @ w2[256,512]^T + b2 + x, fp32 out
__global__ __launch_bounds__(256) void se_gemm2_kernel(
    const ushort* __restrict__ A, const ushort* __restrict__ B,
    const float* __restrict__ b2, const float* __restrict__ xres,
    float* __restrict__ C)
{
    __shared__ __align__(16) ushort As[BMT][LDP];
    __shared__ __align__(16) ushort Bs[BNT][LDP];
    int tid = threadIdx.x;
    int wave = tid >> 6, lane = tid & 63;
    int quad = lane >> 4, l16 = lane & 15;
    int bm = blockIdx.x, bn = blockIdx.y;
    int wm = (wave >> 1) * 64, wn = (wave & 1) * 64;

    floatx4 acc[4][4];
    #pragma unroll
    for (int i = 0; i < 4; i++)
        #pragma unroll
        for (int j = 0; j < 4; j++) acc[i][j] = (floatx4){0.f, 0.f, 0.f, 0.f};

    for (int k0 = 0; k0 < DI; k0 += BKT) {
        __syncthreads();
        #pragma unroll
        for (int t = 0; t < 4; t++) {
            int chunk = tid + 256 * t;
            int r = chunk >> 3;
            int c8 = (chunk & 7) * 8;
            *(uint4*)&As[r][c8] = *(const uint4*)&A[(size_t)(bm * BMT + r) * DI + k0 + c8];
            *(uint4*)&Bs[r][c8] = *(const uint4*)&B[(size_t)(bn * BNT + r) * DI + k0 + c8];
        }
        __syncthreads();
        #pragma unroll
        for (int kk = 0; kk < BKT; kk += 32) {
            bf16x8 af[4], bf[4];
            #pragma unroll
            for (int i = 0; i < 4; i++)
                af[i] = *(const bf16x8*)&As[wm + i * 16 + l16][kk + quad * 8];
            #pragma unroll
            for (int j = 0; j < 4; j++)
                bf[j] = *(const bf16x8*)&Bs[wn + j * 16 + l16][kk + quad * 8];
            #pragma unroll
            for (int i = 0; i < 4; i++)
                #pragma unroll
                for (int j = 0; j < 4; j++)
                    acc[i][j] = __builtin_amdgcn_mfma_f32_16x16x32_bf16(
                        af[i], bf[j], acc[i][j], 0, 0, 0);
        }
    }
    #pragma unroll
    for (int i = 0; i < 4; i++) {
        #pragma unroll
        for (int j = 0; j < 4; j++) {
            int row = bm * BMT + wm + i * 16 + quad * 4;
            int col = bn * BNT + wn + j * 16 + l16;
            float bb = b2[col];
            #pragma unroll
            for (int rr = 0; rr < 4; rr++)
                C[(size_t)(row + rr) * DM + col] =
                    acc[i][j][rr] + bb + xres[(size_t)(row + rr) * DM + col];
        }
    }
}

// ---------------- LayerNorm over 4224 rows: fp32 + bf16 out ----------------
#define LN_ROWS 8
__global__ __launch_bounds__(256) void ln_kernel(
    const float* __restrict__ ys, const float* __restrict__ g,
    const float* __restrict__ b, float* __restrict__ outf,
    ushort* __restrict__ outbf)
{
    int tid = threadIdx.x;
    int wave = tid >> 6, lane = tid & 63;
    int r0 = blockIdx.x * LN_ROWS;
    for (int rr = 0; rr < 2; ++rr) {
        int r = r0 + wave * 2 + rr;
        float vals[4];
        float s = 0.f;
        #pragma unroll
        for (int e = 0; e < 4; e++) {
            vals[e] = ys[(size_t)r * DM + e * 64 + lane];
            s += vals[e];
        }
        #pragma unroll
        for (int off = 32; off; off >>= 1) s += __shfl_xor(s, off);
        float mu = s * (1.f / DM);
        float v = 0.f;
        #pragma unroll
        for (int e = 0; e < 4; e++) { float dd = vals[e] - mu; v += dd * dd; }
        #pragma unroll
        for (int off = 32; off; off >>= 1) v += __shfl_xor(v, off);
        float rstd = rsqrtf(v * (1.f / DM) + 1e-5f);
        #pragma unroll
        for (int e = 0; e < 4; e++) {
            int dd = e * 64 + lane;
            float ov = (vals[e] - mu) * rstd * g[dd] + b[dd];
            outf[(size_t)r * DM + dd] = ov;
            outbf[(size_t)r * DM + dd] = f2bf(ov);
        }
    }
}

// ---------------- support_g = mean over BS rows ----------------
__global__ void sg_reduce_kernel(const float* __restrict__ se_s, float* __restrict__ sg)
{
    int tid = threadIdx.x;
    float a = 0.f;
    for (int r = 0; r < BS; r++) a += se_s[(size_t)r * DM + tid];
    sg[tid] = a * (1.f / BS);
}

// ------- per-gate constants: bsum = b_ih+b_hh ; gadd = bsum + sg@W_hh[:,256:].T -------
__global__ __launch_bounds__(256) void sgw_kernel(
    const float* __restrict__ W_hh, const float* __restrict__ sg,
    const float* __restrict__ b_ih, const float* __restrict__ b_hh,
    float* __restrict__ bsum, float* __restrict__ gadd)
{
    __shared__ float s[DM];
    int tid = threadIdx.x;
    s[tid] = sg[tid];
    __syncthreads();
    int g = blockIdx.x * 256 + tid;
    const float4* w4 = (const float4*)(W_hh + (size_t)g * HH + DM);
    float acc = 0.f;
    for (int f4 = 0; f4 < DM / 4; ++f4) {
        float4 w = w4[f4];
        acc += w.x * s[f4 * 4] + w.y * s[f4 * 4 + 1] + w.z * s[f4 * 4 + 2] + w.w * s[f4 * 4 + 3];
    }
    float bs = b_ih[g] + b_hh[g];
    bsum[g] = bs;
    gadd[g] = bs + acc;
}

// ---------------- LSTM elementwise, step 1 (h_r = 0, c_prev = 0) ----------------
__global__ __launch_bounds__(256) void ew1_kernel(
    const float* __restrict__ P0, const float* __restrict__ bsum,
    const float* __restrict__ qg,
    float* __restrict__ c_ws, float* __restrict__ h_ws, ushort* __restrict__ h_bf)
{
    int row = blockIdx.x;
    const float* p = P0 + (size_t)row * G4;
    int tid = threadIdx.x;
    #pragma unroll
    for (int uu = 0; uu < 2; uu++) {
        int u = tid + uu * 256;
        float iv = p[u] + bsum[u];
        float gv = p[1024 + u] + bsum[1024 + u];
        float cv = sigmoidf_(iv) * tanh_fast(gv);
        c_ws[(size_t)row * HH + u] = cv;
        if (uu == 0) {
            float ov = p[1536 + u] + bsum[1536 + u];
            float hn = sigmoidf_(ov) * tanh_fast(cv);
            float h = qg[(size_t)row * DM + u] + hn;
            h_ws[(size_t)row * DM + u] = h;
            h_bf[(size_t)row * DM + u] = f2bf(h);
        }
    }
}

// ---------------- LSTM elementwise, steps 2..4 ----------------
__global__ __launch_bounds__(256) void ew_kernel(
    const float* __restrict__ P0, const float* __restrict__ P,
    const float* __restrict__ gadd, const float* __restrict__ qg,
    float* __restrict__ c_ws, float* __restrict__ h_ws, ushort* __restrict__ h_bf,
    int write_bf)
{
    int row = blockIdx.x;
    size_t b0 = (size_t)row * G4;
    int tid = threadIdx.x;
    #pragma unroll
    for (int uu = 0; uu < 2; uu++) {
        int u = tid + uu * 256;
        float iv = P0[b0 + u]        + P[b0 + u]        + gadd[u];
        float fv = P0[b0 + 512 + u]  + P[b0 + 512 + u]  + gadd[512 + u];
        float gv = P0[b0 + 1024 + u] + P[b0 + 1024 + u] + gadd[1024 + u];
        size_t cix = (size_t)row * HH + u;
        float cv = sigmoidf_(fv) * c_ws[cix] + sigmoidf_(iv) * tanh_fast(gv);
        c_ws[cix] = cv;
        if (uu == 0) {
            float ov = P0[b0 + 1536 + u] + P[b0 + 1536 + u] + gadd[1536 + u];
            float hn = sigmoidf_(ov) * tanh_fast(cv);
            float h = qg[(size_t)row * DM + u] + hn;
            h_ws[(size_t)row * DM + u] = h;
            if (write_bf) h_bf[(size_t)row * DM + u] = f2bf(h);
        }
    }
}

// ---------------- final cosine ----------------
__global__ __launch_bounds__(256) void final_kernel(
    const float* __restrict__ h_ws, const float* __restrict__ sg,
    float* __restrict__ outp)
{
    __shared__ float sgs[DM];
    int tid = threadIdx.x;
    sgs[tid] = sg[tid];
    __syncthreads();
    int wave = tid >> 6, lane = tid & 63;
    float sn = 0.f;
    #pragma unroll
    for (int e = 0; e < 4; e++) { float v = sgs[e * 64 + lane]; sn += v * v; }
    #pragma unroll
    for (int off = 32; off; off >>= 1) sn += __shfl_xor(sn, off);
    float sgnorm = fmaxf(sqrtf(sn), 1e-12f);

    int row = blockIdx.x * 4 + wave;
    const float* h = h_ws + (size_t)row * DM;
    float dot = 0.f, hn = 0.f;
    #pragma unroll
    for (int e = 0; e < 4; e++) {
        float hv = h[e * 64 + lane];
        dot += hv * sgs[e * 64 + lane];
        hn += hv * hv;
    }
    #pragma unroll
    for (int off = 32; off; off >>= 1) { dot += __shfl_xor(dot, off); hn += __shfl_xor(hn, off); }
    if (lane == 0) outp[row] = dot / (fmaxf(sqrtf(hn), 1e-12f) * sgnorm);
}

extern "C" void kernel_launch(void* const* d_in, const int* in_sizes, int n_in,
                              void* d_out, int out_size, void* d_ws, size_t ws_size,
                              hipStream_t stream)
{
    const int* query    = (const int*)d_in[0];
    const int* support  = (const int*)d_in[1];
    const int* q_l_conn = (const int*)d_in[2];
    const int* q_r_conn = (const int*)d_in[4];
    const int* s_l_conn = (const int*)d_in[6];
    const int* s_r_conn = (const int*)d_in[8];
    const float* emb    = (const float*)d_in[10];
    const float* gcn_W  = (const float*)d_in[11];
    const float* gcn_wb = (const float*)d_in[12];
    const float* gcn_b  = (const float*)d_in[13];
    const float* se_w1  = (const float*)d_in[14];
    const float* se_b1  = (const float*)d_in[15];
    const float* se_w2  = (const float*)d_in[16];
    const float* se_b2  = (const float*)d_in[17];
    const float* ln_g   = (const float*)d_in[18];
    const float* ln_b   = (const float*)d_in[19];
    const float* W_ih   = (const float*)d_in[20];
    const float* W_hh   = (const float*)d_in[21];
    const float* b_ih   = (const float*)d_in[22];
    const float* b_hh   = (const float*)d_in[23];
    float* out = (float*)d_out;

    char* wsb = (char*)d_ws;
    float*  xf     = (float*)wsb;  wsb += (size_t)BM2 * DM * 4;   // gcn fp32 out
    ushort* xb     = (ushort*)wsb; wsb += (size_t)BM2 * DM * 2;   // gcn bf16 out
    ushort* t1_bf  = (ushort*)wsb; wsb += (size_t)BM2 * DI * 2;   // relu(ffn1)
    float*  ys     = (float*)wsb;  wsb += (size_t)BM2 * DM * 4;   // pre-LN
    float*  ln_f   = (float*)wsb;  wsb += (size_t)BM2 * DM * 4;   // post-LN fp32
    ushort* ln_bf  = (ushort*)wsb; wsb += (size_t)BM2 * DM * 2;   // post-LN bf16
    float*  sg     = (float*)wsb;  wsb += DM * 4;
    float*  bsum   = (float*)wsb;  wsb += G4 * 4;
    float*  gadd   = (float*)wsb;  wsb += G4 * 4;
    ushort* wih_bf = (ushort*)wsb; wsb += (size_t)G4 * DM * 2;
    ushort* whh_bf = (ushort*)wsb; wsb += (size_t)G4 * DM * 2;
    ushort* w1_bf  = (ushort*)wsb; wsb += (size_t)DI * DM * 2;
    ushort* w2_bf  = (ushort*)wsb; wsb += (size_t)DM * DI * 2;
    float*  P0     = (float*)wsb;  wsb += (size_t)BQ * G4 * 4;
    float*  P      = (float*)wsb;  wsb += (size_t)BQ * G4 * 4;
    float*  h_ws   = (float*)wsb;  wsb += (size_t)BQ * DM * 4;
    ushort* h_bf   = (ushort*)wsb; wsb += (size_t)BQ * DM * 2;
    float*  c_ws   = (float*)wsb;  wsb += (size_t)BQ * HH * 4;

    // catm [8448][256] aliases the P0 region (dead before first GEMM writes P0)
    float* catm = P0;

    wcvt_kernel<<<G4 * DM / 256, 256, 0, stream>>>(W_ih, W_hh, se_w1, se_w2,
                                                   wih_bf, whh_bf, w1_bf, w2_bf);
    ne_kernel<<<BQ * 2, 256, 0, stream>>>(q_l_conn, q_r_conn, query, emb, catm);
    ne_kernel<<<BS * 2, 256, 0, stream>>>(s_l_conn, s_r_conn, support, emb,
                                          catm + (size_t)BQ * 2 * DM);
    gcn_kernel<<<(BM2 * 2) / GR, 256, 0, stream>>>(catm, gcn_W, gcn_wb, gcn_b,
                                                   xf, xb);
    { dim3 g1(BM2 / BMT, DI / BNT);
      se_gemm1_kernel<<<g1, 256, 0, stream>>>(xb, w1_bf, se_b1, t1_bf); }
    { dim3 g2(BM2 / BMT, DM / BNT);
      se_gemm2_kernel<<<g2, 256, 0, stream>>>(t1_bf, w2_bf, se_b2, xf, ys); }
    ln_kernel<<<BM2 / LN_ROWS, 256, 0, stream>>>(ys, ln_g, ln_b, ln_f, ln_bf);
    sg_reduce_kernel<<<1, 256, 0, stream>>>(ln_f + (size_t)BQ * DM, sg);
    sgw_kernel<<<G4 / 256, 256, 0, stream>>>(W_hh, sg, b_ih, b_hh, bsum, gadd);

    dim3 ggrid(BQ / BMT, GN / BNT);
    gemm_bf16_kernel<<<ggrid, 256, 0, stream>>>(ln_bf, wih_bf, P0);
    ew1_kernel<<<BQ, 256, 0, stream>>>(P0, bsum, ln_f, c_ws, h_ws, h_bf);
    for (int s = 0; s < 3; s++) {
        gemm_bf16_kernel<<<ggrid, 256, 0, stream>>>(h_bf, whh_bf, P);
        ew_kernel<<<BQ, 256, 0, stream>>>(P0, P, gadd, ln_f, c_ws, h_ws, h_bf,
                                          (s < 2) ? 1 : 0);
    }
    final_kernel<<<BQ / 4, 256, 0, stream>>>(h_ws, sg, out);
}